// Round 5
// baseline (29.871 us; speedup 1.0000x reference)
//
#include <hip/hip_runtime.h>

#define NS 32
#define NH 32
#define C2L 2.8853900817779268f  // 2*log2(e): e^(2x) = 2^(C2L*(w1*t+b1))
#define CAP 5120                 // padded bucket capacity (mean 4096, sigma ~64)
#define PARTS 32                 // eval blocks per bucket

// ---- Kernel A: bucket points by floor(t), scatter (t, idx) pairs ----
__global__ __launch_bounds__(256) void bucket_kernel(
    const float* __restrict__ t_in, int2* __restrict__ pairs,
    int* __restrict__ gcount, int N)
{
    __shared__ int lcount[NS];
    __shared__ int lbase[NS];
    const int tid = threadIdx.x;
    if (tid < NS) lcount[tid] = 0;
    __syncthreads();
    const int n = blockIdx.x * 256 + tid;
    float t = 0.f; int b = 0, my = 0;
    const bool v = (n < N);
    if (v) {
        t = t_in[n];
        b = min(max((int)t, 0), NS - 1);
        my = atomicAdd(&lcount[b], 1);          // LDS atomic
    }
    __syncthreads();
    if (tid < NS) lbase[tid] = atomicAdd(&gcount[tid], lcount[tid]);  // 1/block/bucket
    __syncthreads();
    if (v) pairs[b * CAP + lbase[b] + my] = make_int2(__float_as_int(t), n);
}

// ---- Kernel B: evaluate. lane=h, half-wave=point, 4 segs static-unrolled,
// weights in VGPRs (wave-uniform bucket) -> zero LDS in the hot loop. ----
__global__ __launch_bounds__(256) void eval_kernel(
    const int2* __restrict__ pairs, const int* __restrict__ gcount,
    const float* __restrict__ W1, const float* __restrict__ b1,
    const float* __restrict__ W2, const float* __restrict__ b2,
    float* __restrict__ out)
{
    const int f = blockIdx.x / PARTS;      // bucket = floor(t) handled here
    const int part = blockIdx.x % PARTS;
    const int tid = threadIdx.x;
    const int lane = tid & 63;
    const int h = lane & 31;

    // preload the 4 candidate segments' weights (s = f-1+j), zeroed if invalid
    float w1r[4], b1r[4], w2r[4], b2e[4];
    #pragma unroll
    for (int j = 0; j < 4; ++j) {
        const int s = f - 1 + j;
        const bool ok = (s >= 0) && (s < NS);
        const int sc = ok ? s : 0;
        const float w2raw = ok ? W2[sc * NH + h] : 0.f;
        w1r[j] = ok ? W1[sc * NH + h] * C2L : 0.f;
        b1r[j] = ok ? b1[sc * NH + h] * C2L : 0.f;
        w2r[j] = -2.f * w2raw;
        float ssum = w2raw;                 // b2eff = b2[s] + sum_h W2[s][h]
        ssum += __shfl_xor(ssum, 1, 64);
        ssum += __shfl_xor(ssum, 2, 64);
        ssum += __shfl_xor(ssum, 4, 64);
        ssum += __shfl_xor(ssum, 8, 64);
        ssum += __shfl_xor(ssum, 16, 64);
        b2e[j] = ok ? (b2[sc] + ssum) : 0.f;
    }

    const int count = gcount[f];
    const int slots = PARTS * 4;                    // wave-slots per bucket
    const int chunk = (count + slots - 1) / slots;
    const int q = part * 4 + (tid >> 6);
    const int begin = q * chunk;
    const int end = min(begin + chunk, count);
    const int2* bp = pairs + f * CAP;
    const float ff = (float)f;

    for (int base = begin; base < end; base += 64) {
        const int li = base + lane;
        const int2 pr = (li < end) ? bp[li] : make_int2(0, -1);
        const float tv = __int_as_float(pr.x);
        const int   iv = pr.y;
        const int m = (end - base < 64) ? (end - base) : 64;
        for (int i2 = 0; i2 < m; i2 += 2) {
            const int src = i2 + (lane >> 5);       // half-wave picks its point
            const float t  = __shfl(tv, src, 64);
            const int   oi = __shfl(iv, src, 64);
            const bool okh = (src < m);
            // windows for j=0..3 from ONE sin/cos pair:
            // cos(pi*(u+1-j)/2) = {-sin, cos, sin, -cos}(pi*u/2); rev arg = u/4
            const float u  = t - ff;
            const float sn = __builtin_amdgcn_sinf(u * 0.25f);
            const float cs = __builtin_amdgcn_cosf(u * 0.25f);
            const float wj0 = 0.5f - 0.5f * sn;
            const float wj1 = 0.5f + 0.5f * cs;
            const float wj2 = 0.5f + 0.5f * sn;
            const float wj3 = 0.5f - 0.5f * cs;

            const float e0 = __builtin_amdgcn_exp2f(fmaf(t, w1r[0], b1r[0]));
            const float e1 = __builtin_amdgcn_exp2f(fmaf(t, w1r[1], b1r[1]));
            const float e2 = __builtin_amdgcn_exp2f(fmaf(t, w1r[2], b1r[2]));
            const float e3 = __builtin_amdgcn_exp2f(fmaf(t, w1r[3], b1r[3]));
            const float r0 = __builtin_amdgcn_rcpf(e0 + 1.f);
            const float r1 = __builtin_amdgcn_rcpf(e1 + 1.f);
            const float r2 = __builtin_amdgcn_rcpf(e2 + 1.f);
            const float r3 = __builtin_amdgcn_rcpf(e3 + 1.f);
            float tmp =      (wj0 * w2r[0]) * r0;
            tmp = fmaf(wj1 * w2r[1], r1, tmp);
            tmp = fmaf(wj2 * w2r[2], r2, tmp);
            tmp = fmaf(wj3 * w2r[3], r3, tmp);

            tmp = okh ? tmp : 0.f;
            tmp += __shfl_xor(tmp, 1, 64);          // reduce over 32 h-lanes
            tmp += __shfl_xor(tmp, 2, 64);
            tmp += __shfl_xor(tmp, 4, 64);
            tmp += __shfl_xor(tmp, 8, 64);
            tmp += __shfl_xor(tmp, 16, 64);
            if ((lane & 31) == 0 && okh) {
                out[oi] = tmp + wj0 * b2e[0] + wj1 * b2e[1]
                              + wj2 * b2e[2] + wj3 * b2e[3];
            }
        }
    }
}

extern "C" void kernel_launch(void* const* d_in, const int* in_sizes, int n_in,
                              void* d_out, int out_size, void* d_ws, size_t ws_size,
                              hipStream_t stream) {
    const float* t  = (const float*)d_in[0];
    const float* W1 = (const float*)d_in[1];
    const float* b1 = (const float*)d_in[2];
    const float* W2 = (const float*)d_in[3];
    const float* b2 = (const float*)d_in[4];
    float* outp = (float*)d_out;
    const int N = in_sizes[0];

    int2* pairs = (int2*)d_ws;
    int* gcount = (int*)((char*)d_ws + (size_t)NS * CAP * sizeof(int2)); // 256B-aligned

    hipMemsetAsync(gcount, 0, NS * sizeof(int), stream);
    bucket_kernel<<<(N + 255) / 256, 256, 0, stream>>>(t, pairs, gcount, N);
    eval_kernel<<<NS * PARTS, 256, 0, stream>>>(pairs, gcount, W1, b1, W2, b2, outp);
}

// Round 6
// 16.623 us; speedup vs baseline: 1.7970x; 1.7970x over previous
//
#include <hip/hip_runtime.h>

#define NS 32
#define NH 32
#define C2L 2.8853900817779268f  // 2*log2(e): e^(2x) = 2^(C2L*x)

// 2 threads per point: sub=tid&1 handles segments {s0+2*sub, s0+2*sub+1}
// (the 4 segments with nonzero cosine window). Inner loop identical to the
// proven R2 kernel; 4096 waves = 4 waves/SIMD for latency hiding.
// Weights in LDS transposed [h][s] (bank index = s -> conflict-light gather);
// staging uses s-fast decode so LDS writes are conflict-free.
__global__ __launch_bounds__(256) void springnn_kernel(
    const float* __restrict__ t_in,
    const float* __restrict__ W1,   // [S][1][H]
    const float* __restrict__ b1,   // [S][H]
    const float* __restrict__ W2,   // [S][H][1]
    const float* __restrict__ b2,   // [S][1]
    float* __restrict__ out,
    int N)
{
    __shared__ float2 w1b1[NH][NS];  // [h][s] = (W1*C2L, b1*C2L)
    __shared__ float  w2m2[NH][NS];  // [h][s] = -2*W2
    __shared__ float  b2eff[NS];     // b2[s] + sum_h W2[s][h]  (tanh folding)

    const int tid = threadIdx.x;

    // ---- stage weights; s is the fast (lane) index -> conflict-free LDS writes ----
    #pragma unroll
    for (int it = 0; it < 4; ++it) {
        const int idx = it * 256 + tid;
        const int s = idx & (NS - 1);
        const int h = idx >> 5;
        w1b1[h][s] = make_float2(W1[s * NH + h] * C2L, b1[s * NH + h] * C2L);
        w2m2[h][s] = -2.0f * W2[s * NH + h];
    }
    if (tid < NS) {
        float acc = b2[tid];
        const float4* w2v = (const float4*)(W2 + tid * NH);
        #pragma unroll
        for (int q = 0; q < NH / 4; ++q) {
            float4 v = w2v[q];
            acc += (v.x + v.y) + (v.z + v.w);
        }
        b2eff[tid] = acc;
    }
    __syncthreads();

    const int gid = blockIdx.x * 256 + tid;
    const int n = gid >> 1;          // point index
    const int sub = tid & 1;         // segment-pair slot
    if (n >= N) return;
    const float t = t_in[n];

    // s0 = ceil(t-2): the only segments with w>0 are s0..s0+3.
    const int sbase = (int)ceilf(t - 2.0f) + sub * 2;

    float val = 0.0f;
    #pragma unroll
    for (int j = 0; j < 2; ++j) {
        const int s = sbase + j;
        if (s >= 0 && s < NS) {
            // window = (1+cos(pi*d/2))/2 = cos^2(pi*d/4); v_cos takes revolutions
            const float c = __builtin_amdgcn_cosf((t - (float)s) * 0.125f);

            float o0 = b2eff[s], o1 = 0.0f;   // two chains for ILP
            #pragma unroll
            for (int h = 0; h < NH; h += 2) {
                const float2 wa = w1b1[h][s];
                const float2 wb = w1b1[h + 1][s];
                const float ea = __builtin_amdgcn_exp2f(fmaf(t, wa.x, wa.y));
                const float eb = __builtin_amdgcn_exp2f(fmaf(t, wb.x, wb.y));
                o0 = fmaf(w2m2[h][s],     __builtin_amdgcn_rcpf(ea + 1.0f), o0);
                o1 = fmaf(w2m2[h + 1][s], __builtin_amdgcn_rcpf(eb + 1.0f), o1);
            }
            val = fmaf(c * c, o0 + o1, val);
        }
    }

    // combine the two segment-pair partials
    val += __shfl_xor(val, 1, 64);
    if (sub == 0) out[n] = val;
}

extern "C" void kernel_launch(void* const* d_in, const int* in_sizes, int n_in,
                              void* d_out, int out_size, void* d_ws, size_t ws_size,
                              hipStream_t stream) {
    const float* t  = (const float*)d_in[0];
    const float* W1 = (const float*)d_in[1];
    const float* b1 = (const float*)d_in[2];
    const float* W2 = (const float*)d_in[3];
    const float* b2 = (const float*)d_in[4];
    float* outp = (float*)d_out;
    const int N = in_sizes[0];

    const int block = 256;
    const long long threads = (long long)N * 2;
    const int grid = (int)((threads + block - 1) / block);
    springnn_kernel<<<grid, block, 0, stream>>>(t, W1, b1, W2, b2, outp, N);
}

// Round 7
// 12.350 us; speedup vs baseline: 2.4187x; 1.3460x over previous
//
#include <hip/hip_runtime.h>

#define NS 32
#define NH 32
#define C2L 2.8853900817779268f  // 2*log2(e): e^(2x) = 2^(C2L*x)

// 1 thread per point (R2 structure — instruction-optimal: windowing amortizes
// over 64 lanes). Branchless segment mask so all LDS reads are hoistable;
// w2 packed as float2 (b64 reads); padded LDS rows -> 2-way max bank alias
// for both the transposed staging writes and the per-lane s-gather reads.
__global__ __launch_bounds__(256, 2) void springnn_kernel(
    const float* __restrict__ t_in,
    const float* __restrict__ W1,   // [S][1][H]
    const float* __restrict__ b1,   // [S][H]
    const float* __restrict__ W2,   // [S][H][1]
    const float* __restrict__ b2,   // [S][1]
    float* __restrict__ out,
    int N)
{
    __shared__ float2 w1b1[NH][NS + 1];     // [h][s] = (W1*C2L, b1*C2L)
    __shared__ float2 w2p[NH / 2][NS + 1];  // [h2][s] = (-2*W2[2h2], -2*W2[2h2+1])
    __shared__ float  b2eff[NS];            // b2[s] + sum_h W2[s][h] (tanh folding)

    const int tid = threadIdx.x;

    // ---- stage: h-fast decode -> coalesced global; padded rows -> 2-way writes ----
    #pragma unroll
    for (int it = 0; it < 4; ++it) {
        const int idx = it * 256 + tid;
        const int s = idx >> 5;          // wave-uniform-ish (2 values per wave)
        const int h = idx & 31;          // per-lane fast -> coalesced global
        w1b1[h][s] = make_float2(W1[s * NH + h] * C2L, b1[s * NH + h] * C2L);
        ((float*)&w2p[h >> 1][s])[h & 1] = -2.0f * W2[s * NH + h];
    }
    if (tid < NS) {
        float acc = b2[tid];
        const float4* w2v = (const float4*)(W2 + tid * NH);
        #pragma unroll
        for (int q = 0; q < NH / 4; ++q) {
            float4 v = w2v[q];
            acc += (v.x + v.y) + (v.z + v.w);
        }
        b2eff[tid] = acc;
    }
    __syncthreads();

    const int n = blockIdx.x * 256 + tid;
    if (n >= N) return;
    const float t = t_in[n];

    // The only segments with w>0 are s0..s0+3 (d_j = t-s spans (-2,2]).
    const int s0 = (int)ceilf(t - 2.0f);

    float outv = 0.0f;
    #pragma unroll
    for (int j = 0; j < 4; ++j) {
        const int s = s0 + j;
        const bool ok = ((unsigned)s < (unsigned)NS);
        const int sc = ok ? s : 0;                       // clamped: reads unconditional
        // window = (1+cos(pi*d/2))/2 = cos^2(pi*d/4); v_cos takes revolutions
        const float c = __builtin_amdgcn_cosf((t - (float)s) * 0.125f);
        const float w = ok ? c * c : 0.0f;               // mask folded into weight

        float o0 = b2eff[sc], o1 = 0.0f;                 // 2 chains x 4 segs = 8 total
        #pragma unroll
        for (int h2 = 0; h2 < NH / 2; ++h2) {
            const float2 wa = w1b1[2 * h2][sc];
            const float2 wb = w1b1[2 * h2 + 1][sc];
            const float2 wq = w2p[h2][sc];
            const float ea = __builtin_amdgcn_exp2f(fmaf(t, wa.x, wa.y));
            const float eb = __builtin_amdgcn_exp2f(fmaf(t, wb.x, wb.y));
            o0 = fmaf(wq.x, __builtin_amdgcn_rcpf(ea + 1.0f), o0);
            o1 = fmaf(wq.y, __builtin_amdgcn_rcpf(eb + 1.0f), o1);
        }
        outv = fmaf(w, o0 + o1, outv);
    }
    out[n] = outv;
}

extern "C" void kernel_launch(void* const* d_in, const int* in_sizes, int n_in,
                              void* d_out, int out_size, void* d_ws, size_t ws_size,
                              hipStream_t stream) {
    const float* t  = (const float*)d_in[0];
    const float* W1 = (const float*)d_in[1];
    const float* b1 = (const float*)d_in[2];
    const float* W2 = (const float*)d_in[3];
    const float* b2 = (const float*)d_in[4];
    float* outp = (float*)d_out;
    const int N = in_sizes[0];

    const int block = 256;
    const int grid = (N + block - 1) / block;
    springnn_kernel<<<grid, block, 0, stream>>>(t, W1, b1, W2, b2, outp, N);
}